// Round 6
// baseline (185.849 us; speedup 1.0000x reference)
//
#include <hip/hip_runtime.h>
#include <stdint.h>

// Correlation via MFMA. out[b,(dy+4)*9+(dx+4),y,x] = (1/128) sum_c F[c,y,x]*S[c,y+dy,x+dx]
//
// R10: R9's "stage-everything, one barrier, free-run" de-risked to 96KB LDS.
//  R9 (144KB static LDS) failed at container level twice; 128KB is the max
//  in-environment-verified static LDS (m201), so 144KB is the prime suspect.
//  Same theory as R9 (barriers collapse in-flight bytes 5x/block; effective BW
//  pinned at 1.3-1.8 TB/s across R6/R7/R8 = Little's-law latency limit), smaller
//  resource ask:
//  - Tile 16px x 8 rows (R8-verified block: 512 thr, 8 waves). FULL-K B halo
//    staged at once: 16 oc-planes x 16 rows x 24 octs = 6144 uint4 = 96KB LDS.
//  - 12 zero-VGPR global_load_lds DMAs/thread + 32 A-loads, all issued
//    back-to-back -> ~96KB in flight per CU (Little's-law need: ~9KB).
//  - ONE barrier after fill; 40 ds_read_b128 + 40 MFMA with ZERO barriers;
//    one barrier (LDS reuse); per-wave epilogue (no further barriers).
//  - Grid 960 = 8 XCDs x 120, bijective swizzle; epilogue verbatim from R8.
// LESSON (R2): acc[]/fA[] only ever indexed by fully-unrolled loop vars.
// Fallback: if ws_size < 37.5 MB, run the verified R6 kernel (79.6 us).

typedef __attribute__((ext_vector_type(8))) short bf16x8;
typedef __attribute__((ext_vector_type(4))) float f32x4;

constexpr int Bn = 8, Cn = 128, Hn = 96, Wn = 160;
constexpr int CHS = Hn * Wn;
constexpr int YP  = Hn + 8;     // 104 padded rows (y = yp-4)
constexpr int XPD = Wn + 16;    // 176 padded px   (x = xp-8)
constexpr size_t SECP_OCTS  = (size_t)Bn * 16 * YP * XPD;  // 2,342,912 uint4
constexpr size_t SECP_BYTES = SECP_OCTS * 16;              // 37,486,592 B

__device__ __forceinline__ uint32_t bf16rne(float f) {
    uint32_t u = __float_as_uint(f);
    return (u + 0x7FFFu + ((u >> 16) & 1u)) >> 16;
}
__device__ __forceinline__ uint32_t pk(float a, float b) {
    return bf16rne(a) | (bf16rne(b) << 16);
}

// ---------------- prepass: register transpose to bf16 oct-planes (verified) ----
__global__ __launch_bounds__(256)
void prepass(const float* __restrict__ sec, uint4* __restrict__ secp)
{
    const int idx = blockIdx.x * 256 + threadIdx.x;   // == output uint4 index
    const int xp  = idx % XPD;
    const int t1  = idx / XPD;
    const int yp  = t1 % YP;
    const int t2  = t1 / YP;
    const int oc  = t2 & 15;
    const int b   = t2 >> 4;
    const int y = yp - 4, x = xp - 8;
    uint4 o = make_uint4(0u, 0u, 0u, 0u);
    if (y >= 0 && y < Hn && x >= 0 && x < Wn) {
        const float* src = sec + ((size_t)b * Cn + 8 * oc) * CHS + (size_t)y * Wn + x;
        float f[8];
        #pragma unroll
        for (int j = 0; j < 8; ++j) f[j] = src[(size_t)j * CHS];
        o.x = pk(f[0], f[1]); o.y = pk(f[2], f[3]);
        o.z = pk(f[4], f[5]); o.w = pk(f[6], f[7]);
    }
    secp[idx] = o;
}

// ---------------- main: single-barrier full-K MFMA kernel ----------------
// Block 512 thr = 8 waves; wave w = (s = w&1 -> 8px strip, rp = w>>1 -> row pair 0..3).
// Tile 16px x 8 rows; grid (10, 12, 8) = 960 blocks, bijective XCD swizzle (960=8*120).
// Staged: 16 oc-planes x 16 rows x 24 px octs = 6144 uint4 = 96KB.
//   slot sig = oc*384 + row*24 + xw  (yp = y0+row, xp = x0+4+xw). LDS linear in sig.
// Wave output rows Y = y0+2rp+rh (rh = n16>>3), px X = x0+8s+(n16&7).
// B frag for (kc,zi): slot (4kc+quad)*384 + (2rp+zi)*24 + 8s+n16 -> one ds_read_b128.
//   dxc = n16 - px (0..8), dyc = zi - rh (0..8).
__global__ __launch_bounds__(512, 2)
void corrmain(const float* __restrict__ first, const uint4* __restrict__ secp,
              float* __restrict__ out)
{
    __shared__ __align__(16) char smemRaw[98304];   // max(6144*16 stage, 8*1952*4 epi)
    uint4* smemS = (uint4*)smemRaw;
    float* smE   = (float*)smemRaw;

    const int tid  = threadIdx.x;
    const int w    = tid >> 6;
    const int lane = tid & 63;
    const int quad = lane >> 4;
    const int n16  = lane & 15;
    const int s    = w & 1;
    const int rp   = w >> 1;

    // bijective XCD-chunked swizzle: 960 tiles = 8 XCDs x 120; image-major per XCD.
    const int d    = (int)blockIdx.x + 10 * ((int)blockIdx.y + 12 * (int)blockIdx.z);
    const int tile = (d & 7) * 120 + (d >> 3);
    const int b    = tile / 120;
    const int rem  = tile % 120;
    const int y0   = (rem / 10) * 8;
    const int x0   = (rem % 10) * 16;

    // ---- A-loads first: 32 independent named-register loads ----
    const float* fp = first + (size_t)b * Cn * CHS
                    + (size_t)(y0 + 2 * rp + (n16 >> 3)) * Wn
                    + x0 + 8 * s + (n16 & 7);
    float fA[4][8];
    #pragma unroll
    for (int kc = 0; kc < 4; ++kc)
        #pragma unroll
        for (int j = 0; j < 8; ++j)
            fA[kc][j] = fp[(size_t)(32 * kc + 8 * quad + j) * CHS];

    // ---- stage ENTIRE B halo (full K): 12 zero-VGPR DMA loads/thread ----
    // LDS dest: wave-uniform base + lane*16 == linear slot sig = i*512 + tid.
    #pragma unroll
    for (int i = 0; i < 12; ++i) {
        const int sig = i * 512 + tid;
        const int oc  = sig / 384;
        const int rm  = sig % 384;
        const int row = rm / 24;
        const int xw  = rm % 24;
        const int goff = ((b * 16 + oc) * YP + (y0 + row)) * XPD + (x0 + 4 + xw);
        __builtin_amdgcn_global_load_lds(
            (const uint32_t*)(secp + goff),
            (uint32_t*)(smemS + i * 512 + w * 64),
            16, 0, 0);
    }

    // ---- pack A while DMAs fly ----
    bf16x8 aF[4];
    #pragma unroll
    for (int kc = 0; kc < 4; ++kc) {
        union { uint32_t u[4]; bf16x8 v; } cv;
        cv.u[0] = pk(fA[kc][0], fA[kc][1]); cv.u[1] = pk(fA[kc][2], fA[kc][3]);
        cv.u[2] = pk(fA[kc][4], fA[kc][5]); cv.u[3] = pk(fA[kc][6], fA[kc][7]);
        aF[kc] = cv.v;
    }

    f32x4 acc[10];
    #pragma unroll
    for (int zi = 0; zi < 10; ++zi) acc[zi] = (f32x4){0.f, 0.f, 0.f, 0.f};

    __syncthreads();   // the ONE fill barrier (drains DMA vmcnt)

    // ---- compute: 40 ds_read_b128 + 40 MFMA, zero barriers ----
    #pragma unroll
    for (int kc = 0; kc < 4; ++kc) {
        #pragma unroll
        for (int zi = 0; zi < 10; ++zi) {
            union { uint4 u; bf16x8 v; } bf;
            bf.u = smemS[(4 * kc + quad) * 384 + (2 * rp + zi) * 24 + 8 * s + n16];
            acc[zi] = __builtin_amdgcn_mfma_f32_16x16x32_bf16(
                          aF[kc], bf.v, acc[zi], 0, 0, 0);
        }
    }

    __syncthreads();   // staged B dead; epilogue may reuse LDS

    // ---- epilogue (R8-verified): per-wave LDS transpose -> float4 stores ----
    // Per-wave region 1952 floats; written and read by the SAME wave -> no barrier.
    const float inv = 1.0f / 128.0f;
    const int wb = w * 1952;
    #pragma unroll
    for (int zi = 0; zi < 10; ++zi)
        #pragma unroll
        for (int reg = 0; reg < 4; ++reg) {
            const int rh  = quad >> 1;
            const int px  = (quad & 1) * 4 + reg;
            const int dyc = zi - rh;
            const int dxc = n16 - px;
            if (dyc >= 0 && dyc <= 8 && dxc >= 0 && dxc <= 8)
                smE[wb + ((rh * 81) + dyc * 9 + dxc) * 12 + px] = acc[zi][reg] * inv;
        }
    float* ob = out + (size_t)b * 81 * CHS + (size_t)(y0 + 2 * rp) * Wn + x0 + 8 * s;
    #pragma unroll
    for (int ii = 0; ii < 6; ++ii) {
        int slot = lane + ii * 64;
        if (slot < 324) {
            int rh  = (slot >= 162) ? 1 : 0;
            int rm2 = slot - 162 * rh;
            int c   = rm2 >> 1, g = rm2 & 1;
            float4 v = *(const float4*)&smE[wb + (rh * 81 + c) * 12 + 4 * g];
            *(float4*)(ob + (size_t)c * CHS + (size_t)rh * Wn + 4 * g) = v;
        }
    }
}

// ---------------- fallback: verified R6 kernel (79.6 us) ----------------
__global__ __launch_bounds__(512, 4)
void corrfb(const float* __restrict__ first, const float* __restrict__ second,
            float* __restrict__ out)
{
    __shared__ uint4 smem[16 * 32 * 4];

    const int tid  = threadIdx.x;
    const int w    = tid >> 6;
    const int lane = tid & 63;
    const int quad = lane >> 4;
    const int n16  = lane & 15;
    const int r    = w;

    const int d    = (int)blockIdx.x + 10 * ((int)blockIdx.y + 12 * (int)blockIdx.z);
    const int tile = (d & 7) * 120 + (d >> 3);
    const int b    = tile / 120;
    const int rem  = tile % 120;
    const int y0   = (rem / 10) * 8;
    const int x0   = (rem % 10) * 16;
    const int y    = y0 + r;

    const float* sb = second + (size_t)b * Cn * CHS;
    int goff[4], lpos[4];
    bool val[4];
    #pragma unroll
    for (int i = 0; i < 4; ++i) {
        int e   = tid + i * 512;
        int row = e >> 7;
        int xw  = (e >> 2) & 31;
        int q   = e & 3;
        int gy  = y0 + row - 4, gx = x0 + xw - 8;
        val[i]  = (gy >= 0) && (gy < Hn) && (gx >= 0) && (gx < Wn);
        goff[i] = val[i] ? (8 * q * CHS + gy * Wn + gx) : 0;
        lpos[i] = (row * 32 + xw) * 4 + ((q + xw + (xw >> 2)) & 3);
    }

    int bo[2];
    #pragma unroll
    for (int t = 0; t < 2; ++t) {
        int xwr = 16 * t + n16;
        bo[t] = xwr * 4 + ((quad + xwr + (xwr >> 2)) & 3);
    }

    const float* fp = first + (size_t)b * Cn * CHS + (size_t)y * Wn + x0 + n16;

    f32x4 acc[9][2];
    #pragma unroll
    for (int dy = 0; dy < 9; ++dy)
        #pragma unroll
        for (int t = 0; t < 2; ++t)
            acc[dy][t] = (f32x4){0.f, 0.f, 0.f, 0.f};

    float f0[2][8];
    #pragma unroll
    for (int i = 0; i < 2; ++i)
        #pragma unroll
        for (int j = 0; j < 8; ++j)
            f0[i][j] = sb[goff[i] + (size_t)j * CHS];

    #pragma unroll
    for (int kc = 0; kc < 4; ++kc) {
        #pragma unroll
        for (int i = 0; i < 2; ++i) {
            uint4 o;
            o.x = pk(f0[i][0], f0[i][1]); o.y = pk(f0[i][2], f0[i][3]);
            o.z = pk(f0[i][4], f0[i][5]); o.w = pk(f0[i][6], f0[i][7]);
            if (!val[i]) o = make_uint4(0u, 0u, 0u, 0u);
            smem[lpos[i]] = o;
        }
        float f1[2][8], fa[8];
        #pragma unroll
        for (int i = 0; i < 2; ++i)
            #pragma unroll
            for (int j = 0; j < 8; ++j)
                f1[i][j] = sb[goff[2 + i] + (size_t)(32 * kc + j) * CHS];
        #pragma unroll
        for (int j = 0; j < 8; ++j)
            fa[j] = fp[(size_t)(32 * kc + 8 * quad + j) * CHS];
        #pragma unroll
        for (int i = 0; i < 2; ++i) {
            uint4 o;
            o.x = pk(f1[i][0], f1[i][1]); o.y = pk(f1[i][2], f1[i][3]);
            o.z = pk(f1[i][4], f1[i][5]); o.w = pk(f1[i][6], f1[i][7]);
            if (!val[2 + i]) o = make_uint4(0u, 0u, 0u, 0u);
            smem[lpos[2 + i]] = o;
        }
        bf16x8 aF;
        {
            union { uint32_t u[4]; bf16x8 v; } cv;
            cv.u[0] = pk(fa[0], fa[1]); cv.u[1] = pk(fa[2], fa[3]);
            cv.u[2] = pk(fa[4], fa[5]); cv.u[3] = pk(fa[6], fa[7]);
            aF = cv.v;
        }
        __syncthreads();
        if (kc < 3) {
            #pragma unroll
            for (int i = 0; i < 2; ++i)
                #pragma unroll
                for (int j = 0; j < 8; ++j)
                    f0[i][j] = sb[goff[i] + (size_t)(32 * (kc + 1) + j) * CHS];
        }
        #pragma unroll
        for (int dy = 0; dy < 9; ++dy) {
            const int rb = (r + dy) * 128;
            #pragma unroll
            for (int t = 0; t < 2; ++t) {
                union { uint4 u; bf16x8 v; } bf;
                bf.u = smem[rb + bo[t]];
                acc[dy][t] = __builtin_amdgcn_mfma_f32_16x16x32_bf16(
                                 aF, bf.v, acc[dy][t], 0, 0, 0);
            }
        }
        __syncthreads();
    }

    const float inv = 1.0f / 128.0f;
    float* sm = (float*)smem;
    float* ob = out + (size_t)b * 81 * CHS + (size_t)y * Wn + x0;
    const int wb = w * 540;
    #pragma unroll
    for (int ck = 0; ck < 3; ++ck) {
        #pragma unroll
        for (int dd = 0; dd < 3; ++dd)
            #pragma unroll
            for (int t = 0; t < 2; ++t)
                #pragma unroll
                for (int reg = 0; reg < 4; ++reg) {
                    int mm  = quad * 4 + reg;
                    int dxc = 16 * t + n16 - mm - 4;
                    if (dxc >= 0 && dxc <= 8)
                        sm[wb + (dd * 9 + dxc) * 20 + mm] = acc[ck * 3 + dd][t][reg] * inv;
                }
        __syncthreads();
        #pragma unroll
        for (int ii = 0; ii < 2; ++ii) {
            int slot = lane + ii * 64;
            if (slot < 108) {
                int chn = slot >> 2, g = slot & 3;
                float4 v = *(const float4*)&sm[wb + chn * 20 + 4 * g];
                int ch = (ck * 3 + chn / 9) * 9 + chn % 9;
                *(float4*)(ob + (size_t)ch * CHS + 4 * g) = v;
            }
        }
        __syncthreads();
    }
}

extern "C" void kernel_launch(void* const* d_in, const int* in_sizes, int n_in,
                              void* d_out, int out_size, void* d_ws, size_t ws_size,
                              hipStream_t stream) {
    (void)in_sizes; (void)n_in; (void)out_size;
    const float* first  = (const float*)d_in[0];
    const float* second = (const float*)d_in[1];
    float* out = (float*)d_out;

    if (ws_size >= SECP_BYTES) {
        uint4* secp = (uint4*)d_ws;
        prepass<<<dim3((unsigned)(SECP_OCTS / 256), 1, 1), dim3(256, 1, 1), 0, stream>>>(
            second, secp);
        corrmain<<<dim3(10, 12, 8), dim3(512, 1, 1), 0, stream>>>(first, secp, out);
    } else {
        corrfb<<<dim3(Wn / 16, Hn / 8, Bn), dim3(512, 1, 1), 0, stream>>>(
            first, second, out);
    }
}